// Round 4
// baseline (7240.335 us; speedup 1.0000x reference)
//
#include <hip/hip_runtime.h>
#include <cstdint>

#define BATCH   4
#define NPTS    16384
#define NCH     64
#define NPOINT  2048
#define NSAMP   32

// output layout (floats), concatenated in reference return order
#define OFF_XYZ  0                                 // new_xyz      (B,S,3)
#define OFF_IDX1 (BATCH*NPOINT*3)                  // new_xyz_idx  (B,S)    as float
#define OFF_FEAT (OFF_IDX1 + BATCH*NPOINT)         // new_features (B,128,S)
#define OFF_IDX3 (OFF_FEAT + BATCH*128*NPOINT)     // idx          (B,S,32) as float

// Scratch for sorted points lives in the new_features region of d_out
// (1,048,576 floats); mlp_kernel fully overwrites it afterwards.

// Exact float32 squared distance in numpy's evaluation order.
__device__ __forceinline__ float sqd_exact(float dx, float dy, float dz) {
    float a = __fmul_rn(dx, dx);
    float b = __fmul_rn(dy, dy);
    float c = __fmul_rn(dz, dz);
    return __fadd_rn(__fadd_rn(a, b), c);
}

__device__ __forceinline__ int part3(int v) {
    return (v & 1) | ((v & 2) << 2) | ((v & 4) << 4) | ((v & 8) << 6);
}

// Wave64 max of a NONNEGATIVE float via DPP (no LDS). Result broadcast via
// readlane(63). old=0 is the identity since all inputs are >= 0.
__device__ __forceinline__ float wave_max_nonneg(float x) {
    int v;
    v = __builtin_amdgcn_update_dpp(0, __float_as_int(x), 0x111, 0xf, 0xf, false); // row_shr:1
    x = fmaxf(x, __int_as_float(v));
    v = __builtin_amdgcn_update_dpp(0, __float_as_int(x), 0x112, 0xf, 0xf, false); // row_shr:2
    x = fmaxf(x, __int_as_float(v));
    v = __builtin_amdgcn_update_dpp(0, __float_as_int(x), 0x114, 0xf, 0xf, false); // row_shr:4
    x = fmaxf(x, __int_as_float(v));
    v = __builtin_amdgcn_update_dpp(0, __float_as_int(x), 0x118, 0xf, 0xf, false); // row_shr:8
    x = fmaxf(x, __int_as_float(v));
    v = __builtin_amdgcn_update_dpp(0, __float_as_int(x), 0x142, 0xa, 0xf, false); // row_bcast:15
    x = fmaxf(x, __int_as_float(v));
    v = __builtin_amdgcn_update_dpp(0, __float_as_int(x), 0x143, 0xc, 0xf, false); // row_bcast:31
    x = fmaxf(x, __int_as_float(v));
    return __int_as_float(__builtin_amdgcn_readlane(__float_as_int(x), 63));
}

// ---------------------------------------------------------------------------
// Kernel 0: Morton-bin counting sort (per batch).
// ---------------------------------------------------------------------------
__global__ __launch_bounds__(1024)
void binsort_kernel(const float* __restrict__ xyz, float* __restrict__ out) {
    const int b = blockIdx.x, t = threadIdx.x, lane = t & 63, wv = t >> 6;
    float* scr  = out + OFF_FEAT;
    float* sx   = scr + (size_t)b * NPTS;
    float* sy   = scr + (size_t)(BATCH + b) * NPTS;
    float* sz   = scr + (size_t)(2 * BATCH + b) * NPTS;
    int*   sidx = (int*)(scr + (size_t)3 * BATCH * NPTS) + (size_t)b * NPTS;
    const float* xb = xyz + (size_t)b * (NPTS * 3);

    __shared__ int hist[4096];
    __shared__ int wsum[16];
    for (int k = t; k < 4096; k += 1024) hist[k] = 0;
    __syncthreads();

    const int base = t << 4;
    float f[48];
    {
        const float4* v4 = (const float4*)(xb + (size_t)base * 3);
#pragma unroll
        for (int q = 0; q < 12; ++q) {
            float4 v = v4[q];
            f[4*q+0] = v.x; f[4*q+1] = v.y; f[4*q+2] = v.z; f[4*q+3] = v.w;
        }
    }
    int cells[16];
    const float sc = 16.0f / 9.0f;
#pragma unroll
    for (int j = 0; j < 16; ++j) {
        int qx = (int)fminf(fmaxf((f[3*j+0] + 4.5f) * sc, 0.0f), 15.0f);
        int qy = (int)fminf(fmaxf((f[3*j+1] + 4.5f) * sc, 0.0f), 15.0f);
        int qz = (int)fminf(fmaxf((f[3*j+2] + 4.5f) * sc, 0.0f), 15.0f);
        cells[j] = part3(qx) | (part3(qy) << 1) | (part3(qz) << 2);
        atomicAdd(&hist[cells[j]], 1);
    }
    __syncthreads();

    int h0 = hist[4*t], h1 = hist[4*t+1], h2 = hist[4*t+2], h3 = hist[4*t+3];
    int s = h0 + h1 + h2 + h3;
    int ps = s;
#pragma unroll
    for (int off = 1; off <= 32; off <<= 1) {
        int o = __shfl_up(ps, off, 64);
        if (lane >= off) ps += o;
    }
    if (lane == 63) wsum[wv] = ps;
    __syncthreads();
    int wbase = 0;
    for (int w = 0; w < wv; ++w) wbase += wsum[w];
    int excl = wbase + ps - s;
    hist[4*t]   = excl;
    hist[4*t+1] = excl + h0;
    hist[4*t+2] = excl + h0 + h1;
    hist[4*t+3] = excl + h0 + h1 + h2;
    __syncthreads();

#pragma unroll
    for (int j = 0; j < 16; ++j) {
        int pos = atomicAdd(&hist[cells[j]], 1);
        sx[pos] = f[3*j+0]; sy[pos] = f[3*j+1]; sz[pos] = f[3*j+2];
        sidx[pos] = base + j;
    }
}

// ---------------------------------------------------------------------------
// Kernel 1: exact bucket-pruned FPS.
// Per iter: DPP wave-max (no LDS) -> ballot winner lane -> winner writes
// u32 key (f32 bits, nonneg => order-monotone) + float4{x,y,z,idx} ->
// ONE barrier -> all threads read 16 keys as 4x b128 broadcast, register
// argmax (low wave on key-tie; exact rare path resolves by min origidx) ->
// one b128 coord read. No global loads in the loop.
// ---------------------------------------------------------------------------
__global__ __launch_bounds__(1024, 4)
void fps_kernel(const float* __restrict__ xyz, float* __restrict__ out) {
    const int b = blockIdx.x, t = threadIdx.x, wv = t >> 6;
    const float* scr  = out + OFF_FEAT;
    const float* sxp  = scr + (size_t)b * NPTS;
    const float* syp  = scr + (size_t)(BATCH + b) * NPTS;
    const float* szp  = scr + (size_t)(2 * BATCH + b) * NPTS;
    const int*   sip  = (const int*)(scr + (size_t)3 * BATCH * NPTS) + (size_t)b * NPTS;
    const float* __restrict__ xb = xyz + (size_t)b * (NPTS * 3);
    float* oxyz = out + OFF_XYZ  + (size_t)b * (NPOINT * 3);
    float* oidx = out + OFF_IDX1 + (size_t)b * NPOINT;

    const int base = t << 4;
    float px[16], py[16], pz[16], dist[16];
    unsigned idx2[8];
    {
        const float4* vx = (const float4*)(sxp + base);
        const float4* vy = (const float4*)(syp + base);
        const float4* vz = (const float4*)(szp + base);
        const int4*   vi = (const int4*)(sip + base);
#pragma unroll
        for (int q = 0; q < 4; ++q) {
            float4 a = vx[q]; px[4*q] = a.x; px[4*q+1] = a.y; px[4*q+2] = a.z; px[4*q+3] = a.w;
            float4 c = vy[q]; py[4*q] = c.x; py[4*q+1] = c.y; py[4*q+2] = c.z; py[4*q+3] = c.w;
            float4 d = vz[q]; pz[4*q] = d.x; pz[4*q+1] = d.y; pz[4*q+2] = d.z; pz[4*q+3] = d.w;
            int4   i = vi[q];
            idx2[2*q]   = (unsigned)i.x | ((unsigned)i.y << 16);
            idx2[2*q+1] = (unsigned)i.z | ((unsigned)i.w << 16);
        }
    }
    float bnx = px[0], bxx = px[0], bny = py[0], bxy = py[0], bnz = pz[0], bxz = pz[0];
#pragma unroll
    for (int j = 1; j < 16; ++j) {
        bnx = fminf(bnx, px[j]); bxx = fmaxf(bxx, px[j]);
        bny = fminf(bny, py[j]); bxy = fmaxf(bxy, py[j]);
        bnz = fminf(bnz, pz[j]); bxz = fmaxf(bxz, pz[j]);
    }
#pragma unroll
    for (int j = 0; j < 16; ++j) dist[j] = 1e10f;

    float mv = 1e30f;            // cached bucket max (forces activity at it=1)
    int   bi = 0x7FFFFFFF;       // cached min orig idx among bucket max ties
    float wx = px[0], wy = py[0], wz = pz[0];

    __shared__ unsigned s_key[2][16];
    __shared__ __align__(16) float4 s_coord[2][16];

    float cx = xb[0], cy = xb[1], cz = xb[2];
    if (t == 0) { oxyz[0] = cx; oxyz[1] = cy; oxyz[2] = cz; oidx[0] = 0.0f; }

    for (int it = 1; it < NPOINT; ++it) {
        const int q = it & 1;
        // exact skip test vs this bucket's own cached max
        float dxl = fmaxf(fmaxf(bnx - cx, cx - bxx), 0.0f);
        float dyl = fmaxf(fmaxf(bny - cy, cy - bxy), 0.0f);
        float dzl = fmaxf(fmaxf(bnz - cz, cz - bxz), 0.0f);
        float bb  = dxl * dxl + dyl * dyl + dzl * dzl;
        if (bb * 0.99999f < mv) {
            float nmv = -1.0f; int nbi = 0x7FFFFFFF;
            float nwx = px[0], nwy = py[0], nwz = pz[0];
#pragma unroll
            for (int j = 0; j < 16; ++j) {
                float d  = sqd_exact(__fsub_rn(px[j], cx),
                                     __fsub_rn(py[j], cy),
                                     __fsub_rn(pz[j], cz));
                float nd = fminf(dist[j], d);
                dist[j] = nd;
                int oi = (int)((idx2[j >> 1] >> ((j & 1) * 16)) & 0xFFFFu);
                bool better = (nd > nmv) || ((nd == nmv) & (oi < nbi));
                nmv = better ? nd : nmv;
                nbi = better ? oi : nbi;
                nwx = better ? px[j] : nwx;
                nwy = better ? py[j] : nwy;
                nwz = better ? pz[j] : nwz;
            }
            mv = nmv; bi = nbi; wx = nwx; wy = nwy; wz = nwz;
        }
        // wave max via DPP (VALU only)
        float wm = wave_max_nonneg(mv);
        bool cand = (mv == wm);
        unsigned long long msk = __ballot(cand);
        if (__popcll(msk) > 1) {          // exact rare in-wave tie: min origidx
            int tb = 0x7FFFFFFF;
            unsigned long long m2 = msk;
            while (m2) {
                int l = __ffsll(m2) - 1;
                int obi = __shfl(bi, l, 64);
                tb = min(tb, obi);
                m2 &= m2 - 1;
            }
            cand = cand && (bi == tb);
        }
        if (cand) {
            s_key[q][wv]   = __float_as_uint(mv);
            s_coord[q][wv] = make_float4(wx, wy, wz, __int_as_float(bi));
        }
        __syncthreads();
        // all threads: 16 keys as 4 x b128 broadcast reads, register argmax
        const uint4* kp = (const uint4*)&s_key[q][0];
        uint4 k0 = kp[0], k1 = kp[1], k2 = kp[2], k3 = kp[3];
        unsigned kk[16] = { k0.x, k0.y, k0.z, k0.w, k1.x, k1.y, k1.z, k1.w,
                            k2.x, k2.y, k2.z, k2.w, k3.x, k3.y, k3.z, k3.w };
        unsigned bk = kk[0]; int bw = 0;
#pragma unroll
        for (int i = 1; i < 16; ++i) {
            bool g = kk[i] > bk;          // strict >: low wave kept on tie
            bk = g ? kk[i] : bk;
            bw = g ? i     : bw;
        }
        int cnt = 0;
#pragma unroll
        for (int i = 0; i < 16; ++i) cnt += (kk[i] == bk);
        if (cnt > 1) {                    // exact rare cross-wave tie
            int bidx = 0x7FFFFFFF, bw2 = bw;
            for (int i = 0; i < 16; ++i) {
                if (kk[i] == bk) {
                    float4 c = s_coord[q][i];
                    int ii = __float_as_int(c.w);
                    if (ii < bidx) { bidx = ii; bw2 = i; }
                }
            }
            bw = bw2;
        }
        float4 f = s_coord[q][bw];
        cx = f.x; cy = f.y; cz = f.z;
        if (t == 0) {
            oxyz[it*3+0] = cx; oxyz[it*3+1] = cy; oxyz[it*3+2] = cz;
            oidx[it] = (float)__float_as_int(f.w);
        }
    }
}

// ---------------------------------------------------------------------------
// Kernel 2: ball query (unchanged).
// ---------------------------------------------------------------------------
__global__ __launch_bounds__(256)
void ballq_kernel(const float* __restrict__ xyz, float* __restrict__ out) {
    const int b    = blockIdx.y;
    const int t    = threadIdx.x;
    const int lane = t & 63;
    const int wv   = t >> 6;
    const int s    = blockIdx.x * 4 + wv;
    const float* __restrict__ xb = xyz + (size_t)b * (NPTS * 3);

    const float* ctr = out + OFF_XYZ + ((size_t)(b * NPOINT + s)) * 3;
    const float cx = ctr[0], cy = ctr[1], cz = ctr[2];

    __shared__ float sx[256], sy[256], sz[256];
    __shared__ int   lists[4][NSAMP];

    int have = 0;
    for (int tile = 0; tile < NPTS / 256; ++tile) {
        const int pi = tile * 256 + t;
        const float* p = xb + (size_t)pi * 3;
        float ax = p[0], ay = p[1], az = p[2];
        sx[t] = ax; sy[t] = ay; sz[t] = az;
        __syncthreads();
        if (have < NSAMP) {
#pragma unroll
            for (int sub = 0; sub < 4; ++sub) {
                const int li = sub * 64 + lane;
                float d2 = sqd_exact(__fsub_rn(cx, sx[li]),
                                     __fsub_rn(cy, sy[li]),
                                     __fsub_rn(cz, sz[li]));
                bool hit = d2 < 0.04f;
                unsigned long long m = __ballot(hit);
                if (hit) {
                    int pos = have + (int)__popcll(m & ((1ull << lane) - 1ull));
                    if (pos < NSAMP) lists[wv][pos] = tile * 256 + li;
                }
                have += (int)__popcll(m);
                if (have >= NSAMP) break;
            }
        }
        __syncthreads();
    }
    if (lane < NSAMP) {
        int hv = have < NSAMP ? have : NSAMP;
        int v0 = (have > 0) ? lists[wv][0] : 0;
        int v  = (lane < hv) ? lists[wv][lane] : v0;
        out[OFF_IDX3 + ((size_t)(b * NPOINT + s)) * NSAMP + lane] = (float)v;
    }
}

// ---------------------------------------------------------------------------
// Kernel 3: gather + 3-layer MLP + max over samples (unchanged).
// ---------------------------------------------------------------------------
__global__ __launch_bounds__(256)
void mlp_kernel(const float* __restrict__ xyz, const float* __restrict__ feat,
                const float* __restrict__ W1, const float* __restrict__ b1,
                const float* __restrict__ W2, const float* __restrict__ b2,
                const float* __restrict__ W3, const float* __restrict__ b3,
                float* __restrict__ out) {
    const int s = blockIdx.x;
    const int b = blockIdx.y;
    const int t = threadIdx.x;

    __shared__ __align__(16) float Wbuf[64 * 128];
    __shared__ float Xs[67 * 32];
    __shared__ float H1[64 * 32];
    __shared__ float H2[64 * 32];
    __shared__ int   idxs[NSAMP];
    __shared__ float ctr[3];

    if (t < NSAMP) idxs[t] = (int)out[OFF_IDX3 + ((size_t)(b * NPOINT + s)) * NSAMP + t];
    if (t < 3)     ctr[t]  = out[OFF_XYZ + ((size_t)(b * NPOINT + s)) * 3 + t];
    for (int k = t; k < 67 * 64; k += 256) {
        int i = k >> 6, o = k & 63;
        Wbuf[k] = W1[o * 67 + i];
    }
    __syncthreads();

    const float* xb = xyz  + (size_t)b * (NPTS * 3);
    const float* fb = feat + (size_t)b * (NCH * NPTS);
    for (int k = t; k < 67 * 32; k += 256) {
        int i = k >> 5, n = k & 31;
        int ii = idxs[n];
        float v;
        if (i < 3) v = __fsub_rn(xb[(size_t)ii * 3 + i], ctr[i]);
        else       v = fb[(size_t)(i - 3) * NPTS + ii];
        Xs[k] = v;
    }
    __syncthreads();

    const int n  = t & 31;
    const int og = t >> 5;

    {
        const int o0 = og * 8;
        float acc[8] = {0,0,0,0,0,0,0,0};
        for (int i = 0; i < 67; ++i) {
            float x = Xs[i * 32 + n];
            const float4* wp = (const float4*)&Wbuf[i * 64 + o0];
            float4 w0 = wp[0], w1 = wp[1];
            acc[0] += w0.x * x; acc[1] += w0.y * x; acc[2] += w0.z * x; acc[3] += w0.w * x;
            acc[4] += w1.x * x; acc[5] += w1.y * x; acc[6] += w1.z * x; acc[7] += w1.w * x;
        }
#pragma unroll
        for (int k = 0; k < 8; ++k)
            H1[(o0 + k) * 32 + n] = fmaxf(acc[k] + b1[o0 + k], 0.0f);
    }
    __syncthreads();
    for (int k = t; k < 64 * 64; k += 256) {
        int i = k >> 6, o = k & 63;
        Wbuf[k] = W2[o * 64 + i];
    }
    __syncthreads();

    {
        const int o0 = og * 8;
        float acc[8] = {0,0,0,0,0,0,0,0};
        for (int i = 0; i < 64; ++i) {
            float x = H1[i * 32 + n];
            const float4* wp = (const float4*)&Wbuf[i * 64 + o0];
            float4 w0 = wp[0], w1 = wp[1];
            acc[0] += w0.x * x; acc[1] += w0.y * x; acc[2] += w0.z * x; acc[3] += w0.w * x;
            acc[4] += w1.x * x; acc[5] += w1.y * x; acc[6] += w1.z * x; acc[7] += w1.w * x;
        }
#pragma unroll
        for (int k = 0; k < 8; ++k)
            H2[(o0 + k) * 32 + n] = fmaxf(acc[k] + b2[o0 + k], 0.0f);
    }
    __syncthreads();
    for (int k = t; k < 64 * 128; k += 256) {
        int i = k >> 7, o = k & 127;
        Wbuf[k] = W3[o * 64 + i];
    }
    __syncthreads();

    {
        const int o0 = og * 16;
        float acc[16];
#pragma unroll
        for (int k = 0; k < 16; ++k) acc[k] = 0.0f;
        for (int i = 0; i < 64; ++i) {
            float x = H2[i * 32 + n];
            const float4* wp = (const float4*)&Wbuf[i * 128 + o0];
            float4 w0 = wp[0], w1 = wp[1], w2 = wp[2], w3 = wp[3];
            acc[0]  += w0.x * x; acc[1]  += w0.y * x; acc[2]  += w0.z * x; acc[3]  += w0.w * x;
            acc[4]  += w1.x * x; acc[5]  += w1.y * x; acc[6]  += w1.z * x; acc[7]  += w1.w * x;
            acc[8]  += w2.x * x; acc[9]  += w2.y * x; acc[10] += w2.z * x; acc[11] += w2.w * x;
            acc[12] += w3.x * x; acc[13] += w3.y * x; acc[14] += w3.z * x; acc[15] += w3.w * x;
        }
#pragma unroll
        for (int k = 0; k < 16; ++k) {
            float h = fmaxf(acc[k] + b3[o0 + k], 0.0f);
#pragma unroll
            for (int off = 16; off >= 1; off >>= 1)
                h = fmaxf(h, __shfl_xor(h, off, 64));
            if (n == 0)
                out[OFF_FEAT + (size_t)b * 128 * NPOINT + (size_t)(o0 + k) * NPOINT + s] = h;
        }
    }
}

extern "C" void kernel_launch(void* const* d_in, const int* in_sizes, int n_in,
                              void* d_out, int out_size, void* d_ws, size_t ws_size,
                              hipStream_t stream) {
    const float* xyz  = (const float*)d_in[0];
    const float* feat = (const float*)d_in[1];
    const float* W1   = (const float*)d_in[2];
    const float* b1   = (const float*)d_in[3];
    const float* W2   = (const float*)d_in[4];
    const float* b2   = (const float*)d_in[5];
    const float* W3   = (const float*)d_in[6];
    const float* b3   = (const float*)d_in[7];
    float* out = (float*)d_out;

    binsort_kernel<<<BATCH, 1024, 0, stream>>>(xyz, out);
    fps_kernel<<<BATCH, 1024, 0, stream>>>(xyz, out);
    ballq_kernel<<<dim3(NPOINT / 4, BATCH), 256, 0, stream>>>(xyz, out);
    mlp_kernel<<<dim3(NPOINT, BATCH), 256, 0, stream>>>(xyz, feat, W1, b1, W2, b2, W3, b3, out);
}

// Round 5
// 3042.715 us; speedup vs baseline: 2.3796x; 2.3796x over previous
//
#include <hip/hip_runtime.h>
#include <cstdint>

#define BATCH   4
#define NPTS    16384
#define NCH     64
#define NPOINT  2048
#define NSAMP   32

// output layout (floats), concatenated in reference return order
#define OFF_XYZ  0                                 // new_xyz      (B,S,3)
#define OFF_IDX1 (BATCH*NPOINT*3)                  // new_xyz_idx  (B,S)    as float
#define OFF_FEAT (OFF_IDX1 + BATCH*NPOINT)         // new_features (B,128,S)
#define OFF_IDX3 (OFF_FEAT + BATCH*128*NPOINT)     // idx          (B,S,32) as float

// Scratch for sorted points lives in the new_features region of d_out
// (1,048,576 floats); mlp_kernel fully overwrites it afterwards.

// Exact float32 squared distance in numpy's evaluation order.
__device__ __forceinline__ float sqd_exact(float dx, float dy, float dz) {
    float a = __fmul_rn(dx, dx);
    float b = __fmul_rn(dy, dy);
    float c = __fmul_rn(dz, dz);
    return __fadd_rn(__fadd_rn(a, b), c);
}

__device__ __forceinline__ int part3(int v) {
    return (v & 1) | ((v & 2) << 2) | ((v & 4) << 4) | ((v & 8) << 6);
}

// Wave64 max of a NONNEGATIVE float via DPP (no LDS). Result broadcast via
// readlane(63). old=0 is the identity since all inputs are >= 0.
// (Validated bit-exact in round 4: absmax 0.)
__device__ __forceinline__ float wave_max_nonneg(float x) {
    int v;
    v = __builtin_amdgcn_update_dpp(0, __float_as_int(x), 0x111, 0xf, 0xf, false); // row_shr:1
    x = fmaxf(x, __int_as_float(v));
    v = __builtin_amdgcn_update_dpp(0, __float_as_int(x), 0x112, 0xf, 0xf, false); // row_shr:2
    x = fmaxf(x, __int_as_float(v));
    v = __builtin_amdgcn_update_dpp(0, __float_as_int(x), 0x114, 0xf, 0xf, false); // row_shr:4
    x = fmaxf(x, __int_as_float(v));
    v = __builtin_amdgcn_update_dpp(0, __float_as_int(x), 0x118, 0xf, 0xf, false); // row_shr:8
    x = fmaxf(x, __int_as_float(v));
    v = __builtin_amdgcn_update_dpp(0, __float_as_int(x), 0x142, 0xa, 0xf, false); // row_bcast:15
    x = fmaxf(x, __int_as_float(v));
    v = __builtin_amdgcn_update_dpp(0, __float_as_int(x), 0x143, 0xc, 0xf, false); // row_bcast:31
    x = fmaxf(x, __int_as_float(v));
    return __int_as_float(__builtin_amdgcn_readlane(__float_as_int(x), 63));
}

// ---------------------------------------------------------------------------
// Kernel 0: Morton-bin counting sort (per batch).
// ---------------------------------------------------------------------------
__global__ __launch_bounds__(1024)
void binsort_kernel(const float* __restrict__ xyz, float* __restrict__ out) {
    const int b = blockIdx.x, t = threadIdx.x, lane = t & 63, wv = t >> 6;
    float* scr  = out + OFF_FEAT;
    float* sx   = scr + (size_t)b * NPTS;
    float* sy   = scr + (size_t)(BATCH + b) * NPTS;
    float* sz   = scr + (size_t)(2 * BATCH + b) * NPTS;
    int*   sidx = (int*)(scr + (size_t)3 * BATCH * NPTS) + (size_t)b * NPTS;
    const float* xb = xyz + (size_t)b * (NPTS * 3);

    __shared__ int hist[4096];
    __shared__ int wsum[16];
    for (int k = t; k < 4096; k += 1024) hist[k] = 0;
    __syncthreads();

    const int base = t << 4;
    float f[48];
    {
        const float4* v4 = (const float4*)(xb + (size_t)base * 3);
#pragma unroll
        for (int q = 0; q < 12; ++q) {
            float4 v = v4[q];
            f[4*q+0] = v.x; f[4*q+1] = v.y; f[4*q+2] = v.z; f[4*q+3] = v.w;
        }
    }
    int cells[16];
    const float sc = 16.0f / 9.0f;
#pragma unroll
    for (int j = 0; j < 16; ++j) {
        int qx = (int)fminf(fmaxf((f[3*j+0] + 4.5f) * sc, 0.0f), 15.0f);
        int qy = (int)fminf(fmaxf((f[3*j+1] + 4.5f) * sc, 0.0f), 15.0f);
        int qz = (int)fminf(fmaxf((f[3*j+2] + 4.5f) * sc, 0.0f), 15.0f);
        cells[j] = part3(qx) | (part3(qy) << 1) | (part3(qz) << 2);
        atomicAdd(&hist[cells[j]], 1);
    }
    __syncthreads();

    int h0 = hist[4*t], h1 = hist[4*t+1], h2 = hist[4*t+2], h3 = hist[4*t+3];
    int s = h0 + h1 + h2 + h3;
    int ps = s;
#pragma unroll
    for (int off = 1; off <= 32; off <<= 1) {
        int o = __shfl_up(ps, off, 64);
        if (lane >= off) ps += o;
    }
    if (lane == 63) wsum[wv] = ps;
    __syncthreads();
    int wbase = 0;
    for (int w = 0; w < wv; ++w) wbase += wsum[w];
    int excl = wbase + ps - s;
    hist[4*t]   = excl;
    hist[4*t+1] = excl + h0;
    hist[4*t+2] = excl + h0 + h1;
    hist[4*t+3] = excl + h0 + h1 + h2;
    __syncthreads();

#pragma unroll
    for (int j = 0; j < 16; ++j) {
        int pos = atomicAdd(&hist[cells[j]], 1);
        sx[pos] = f[3*j+0]; sy[pos] = f[3*j+1]; sz[pos] = f[3*j+2];
        sidx[pos] = base + j;
    }
}

// ---------------------------------------------------------------------------
// Kernel 1: exact bucket-pruned FPS — round-2 structure (best so far) with
// ONE surgical change: the 6-stage u64 shfl butterfly (12 dependent
// ds_bpermutes) is replaced by a VALU-only DPP f32 max + ballot leader
// election. Everything else (u64 cached key mk, separate tie-extract loop,
// post-barrier 16 x ds_read_b64 scan, global center load) is R2-verbatim.
// launch_bounds has no min-wave clamp: only 1 block/CU runs, give the
// allocator the full register budget so nothing spills to scratch.
// ---------------------------------------------------------------------------
__global__ __launch_bounds__(1024)
void fps_kernel(const float* __restrict__ xyz, float* __restrict__ out) {
    const int b = blockIdx.x, t = threadIdx.x, wv = t >> 6;
    const float* scr  = out + OFF_FEAT;
    const float* sxp  = scr + (size_t)b * NPTS;
    const float* syp  = scr + (size_t)(BATCH + b) * NPTS;
    const float* szp  = scr + (size_t)(2 * BATCH + b) * NPTS;
    const int*   sip  = (const int*)(scr + (size_t)3 * BATCH * NPTS) + (size_t)b * NPTS;
    const float* __restrict__ xb = xyz + (size_t)b * (NPTS * 3);
    float* oxyz = out + OFF_XYZ  + (size_t)b * (NPOINT * 3);
    float* oidx = out + OFF_IDX1 + (size_t)b * NPOINT;

    const int base = t << 4;
    float px[16], py[16], pz[16], dist[16];
    unsigned idx2[8];
    {
        const float4* vx = (const float4*)(sxp + base);
        const float4* vy = (const float4*)(syp + base);
        const float4* vz = (const float4*)(szp + base);
        const int4*   vi = (const int4*)(sip + base);
#pragma unroll
        for (int q = 0; q < 4; ++q) {
            float4 a = vx[q]; px[4*q] = a.x; px[4*q+1] = a.y; px[4*q+2] = a.z; px[4*q+3] = a.w;
            float4 c = vy[q]; py[4*q] = c.x; py[4*q+1] = c.y; py[4*q+2] = c.z; py[4*q+3] = c.w;
            float4 d = vz[q]; pz[4*q] = d.x; pz[4*q+1] = d.y; pz[4*q+2] = d.z; pz[4*q+3] = d.w;
            int4   i = vi[q];
            idx2[2*q]   = (unsigned)i.x | ((unsigned)i.y << 16);
            idx2[2*q+1] = (unsigned)i.z | ((unsigned)i.w << 16);
        }
    }
    float bnx = px[0], bxx = px[0], bny = py[0], bxy = py[0], bnz = pz[0], bxz = pz[0];
#pragma unroll
    for (int j = 1; j < 16; ++j) {
        bnx = fminf(bnx, px[j]); bxx = fmaxf(bxx, px[j]);
        bny = fminf(bny, py[j]); bxy = fmaxf(bxy, py[j]);
        bnz = fminf(bnz, pz[j]); bxz = fmaxf(bxz, pz[j]);
    }
#pragma unroll
    for (int j = 0; j < 16; ++j) dist[j] = 1e10f;
    unsigned long long mk = 0;      // recomputed at it=1 (all buckets active then)
    float maxdG = 1e10f;

    __shared__ unsigned long long s_k[2][16];

    float cx = xb[0], cy = xb[1], cz = xb[2];
    if (t == 0) { oxyz[0] = cx; oxyz[1] = cy; oxyz[2] = cz; oidx[0] = 0.0f; }

    for (int it = 1; it < NPOINT; ++it) {
        const int q = it & 1;
        float dxl = fmaxf(fmaxf(bnx - cx, cx - bxx), 0.0f);
        float dyl = fmaxf(fmaxf(bny - cy, cy - bxy), 0.0f);
        float dzl = fmaxf(fmaxf(bnz - cz, cz - bxz), 0.0f);
        float bb  = dxl * dxl + dyl * dyl + dzl * dzl;
        if (bb * 0.99999f < maxdG) {          // bucket must update (exact test)
            float mv = 0.0f;
#pragma unroll
            for (int j = 0; j < 16; ++j) {
                float d  = sqd_exact(__fsub_rn(px[j], cx),
                                     __fsub_rn(py[j], cy),
                                     __fsub_rn(pz[j], cz));
                float nd = fminf(dist[j], d);
                dist[j] = nd;
                mv = fmaxf(mv, nd);
            }
            int bi = 0xFFFF;                  // min orig idx among value-ties
#pragma unroll
            for (int j = 0; j < 16; ++j) {
                int oi = (int)((idx2[j >> 1] >> ((j & 1) * 16)) & 0xFFFFu);
                if (dist[j] == mv) bi = min(bi, oi);
            }
            mk = ((unsigned long long)__float_as_uint(mv) << 32) | (unsigned)(~bi);
            maxdG = mv;
        }
        // wave max via DPP (VALU only) + ballot leader election
        float wm = wave_max_nonneg(maxdG);
        bool cand = (maxdG == wm);
        unsigned long long msk = __ballot(cand);
        if (__popcll(msk) > 1) {              // exact rare in-wave tie path
            unsigned long long best = 0;
            unsigned long long m2 = msk;
            while (m2) {
                int l = __ffsll(m2) - 1;
                unsigned long long omk = __shfl(mk, l, 64);
                best = best > omk ? best : omk;    // max mk == min orig idx
                m2 &= m2 - 1;
            }
            cand = cand && (mk == best);      // mk unique -> unique leader
        }
        if (cand) s_k[q][wv] = mk;
        __syncthreads();
        unsigned long long gk = s_k[q][0];
#pragma unroll
        for (int w = 1; w < 16; ++w) {
            unsigned long long v = s_k[q][w];
            if (v > gk) gk = v;
        }
        const int gi = (int)(~(unsigned)gk);  // orig index in [0,16384)
        cx = xb[gi*3+0]; cy = xb[gi*3+1]; cz = xb[gi*3+2];
        if (t == 0) {
            oxyz[it*3+0] = cx; oxyz[it*3+1] = cy; oxyz[it*3+2] = cz;
            oidx[it] = (float)gi;
        }
    }
}

// ---------------------------------------------------------------------------
// Kernel 2: ball query (unchanged).
// ---------------------------------------------------------------------------
__global__ __launch_bounds__(256)
void ballq_kernel(const float* __restrict__ xyz, float* __restrict__ out) {
    const int b    = blockIdx.y;
    const int t    = threadIdx.x;
    const int lane = t & 63;
    const int wv   = t >> 6;
    const int s    = blockIdx.x * 4 + wv;
    const float* __restrict__ xb = xyz + (size_t)b * (NPTS * 3);

    const float* ctr = out + OFF_XYZ + ((size_t)(b * NPOINT + s)) * 3;
    const float cx = ctr[0], cy = ctr[1], cz = ctr[2];

    __shared__ float sx[256], sy[256], sz[256];
    __shared__ int   lists[4][NSAMP];

    int have = 0;
    for (int tile = 0; tile < NPTS / 256; ++tile) {
        const int pi = tile * 256 + t;
        const float* p = xb + (size_t)pi * 3;
        float ax = p[0], ay = p[1], az = p[2];
        sx[t] = ax; sy[t] = ay; sz[t] = az;
        __syncthreads();
        if (have < NSAMP) {
#pragma unroll
            for (int sub = 0; sub < 4; ++sub) {
                const int li = sub * 64 + lane;
                float d2 = sqd_exact(__fsub_rn(cx, sx[li]),
                                     __fsub_rn(cy, sy[li]),
                                     __fsub_rn(cz, sz[li]));
                bool hit = d2 < 0.04f;
                unsigned long long m = __ballot(hit);
                if (hit) {
                    int pos = have + (int)__popcll(m & ((1ull << lane) - 1ull));
                    if (pos < NSAMP) lists[wv][pos] = tile * 256 + li;
                }
                have += (int)__popcll(m);
                if (have >= NSAMP) break;
            }
        }
        __syncthreads();
    }
    if (lane < NSAMP) {
        int hv = have < NSAMP ? have : NSAMP;
        int v0 = (have > 0) ? lists[wv][0] : 0;
        int v  = (lane < hv) ? lists[wv][lane] : v0;
        out[OFF_IDX3 + ((size_t)(b * NPOINT + s)) * NSAMP + lane] = (float)v;
    }
}

// ---------------------------------------------------------------------------
// Kernel 3: gather + 3-layer MLP + max over samples (unchanged).
// ---------------------------------------------------------------------------
__global__ __launch_bounds__(256)
void mlp_kernel(const float* __restrict__ xyz, const float* __restrict__ feat,
                const float* __restrict__ W1, const float* __restrict__ b1,
                const float* __restrict__ W2, const float* __restrict__ b2,
                const float* __restrict__ W3, const float* __restrict__ b3,
                float* __restrict__ out) {
    const int s = blockIdx.x;
    const int b = blockIdx.y;
    const int t = threadIdx.x;

    __shared__ __align__(16) float Wbuf[64 * 128];
    __shared__ float Xs[67 * 32];
    __shared__ float H1[64 * 32];
    __shared__ float H2[64 * 32];
    __shared__ int   idxs[NSAMP];
    __shared__ float ctr[3];

    if (t < NSAMP) idxs[t] = (int)out[OFF_IDX3 + ((size_t)(b * NPOINT + s)) * NSAMP + t];
    if (t < 3)     ctr[t]  = out[OFF_XYZ + ((size_t)(b * NPOINT + s)) * 3 + t];
    for (int k = t; k < 67 * 64; k += 256) {
        int i = k >> 6, o = k & 63;
        Wbuf[k] = W1[o * 67 + i];
    }
    __syncthreads();

    const float* xb = xyz  + (size_t)b * (NPTS * 3);
    const float* fb = feat + (size_t)b * (NCH * NPTS);
    for (int k = t; k < 67 * 32; k += 256) {
        int i = k >> 5, n = k & 31;
        int ii = idxs[n];
        float v;
        if (i < 3) v = __fsub_rn(xb[(size_t)ii * 3 + i], ctr[i]);
        else       v = fb[(size_t)(i - 3) * NPTS + ii];
        Xs[k] = v;
    }
    __syncthreads();

    const int n  = t & 31;
    const int og = t >> 5;

    {
        const int o0 = og * 8;
        float acc[8] = {0,0,0,0,0,0,0,0};
        for (int i = 0; i < 67; ++i) {
            float x = Xs[i * 32 + n];
            const float4* wp = (const float4*)&Wbuf[i * 64 + o0];
            float4 w0 = wp[0], w1 = wp[1];
            acc[0] += w0.x * x; acc[1] += w0.y * x; acc[2] += w0.z * x; acc[3] += w0.w * x;
            acc[4] += w1.x * x; acc[5] += w1.y * x; acc[6] += w1.z * x; acc[7] += w1.w * x;
        }
#pragma unroll
        for (int k = 0; k < 8; ++k)
            H1[(o0 + k) * 32 + n] = fmaxf(acc[k] + b1[o0 + k], 0.0f);
    }
    __syncthreads();
    for (int k = t; k < 64 * 64; k += 256) {
        int i = k >> 6, o = k & 63;
        Wbuf[k] = W2[o * 64 + i];
    }
    __syncthreads();

    {
        const int o0 = og * 8;
        float acc[8] = {0,0,0,0,0,0,0,0};
        for (int i = 0; i < 64; ++i) {
            float x = H1[i * 32 + n];
            const float4* wp = (const float4*)&Wbuf[i * 64 + o0];
            float4 w0 = wp[0], w1 = wp[1];
            acc[0] += w0.x * x; acc[1] += w0.y * x; acc[2] += w0.z * x; acc[3] += w0.w * x;
            acc[4] += w1.x * x; acc[5] += w1.y * x; acc[6] += w1.z * x; acc[7] += w1.w * x;
        }
#pragma unroll
        for (int k = 0; k < 8; ++k)
            H2[(o0 + k) * 32 + n] = fmaxf(acc[k] + b2[o0 + k], 0.0f);
    }
    __syncthreads();
    for (int k = t; k < 64 * 128; k += 256) {
        int i = k >> 7, o = k & 127;
        Wbuf[k] = W3[o * 64 + i];
    }
    __syncthreads();

    {
        const int o0 = og * 16;
        float acc[16];
#pragma unroll
        for (int k = 0; k < 16; ++k) acc[k] = 0.0f;
        for (int i = 0; i < 64; ++i) {
            float x = H2[i * 32 + n];
            const float4* wp = (const float4*)&Wbuf[i * 128 + o0];
            float4 w0 = wp[0], w1 = wp[1], w2 = wp[2], w3 = wp[3];
            acc[0]  += w0.x * x; acc[1]  += w0.y * x; acc[2]  += w0.z * x; acc[3]  += w0.w * x;
            acc[4]  += w1.x * x; acc[5]  += w1.y * x; acc[6]  += w1.z * x; acc[7]  += w1.w * x;
            acc[8]  += w2.x * x; acc[9]  += w2.y * x; acc[10] += w2.z * x; acc[11] += w2.w * x;
            acc[12] += w3.x * x; acc[13] += w3.y * x; acc[14] += w3.z * x; acc[15] += w3.w * x;
        }
#pragma unroll
        for (int k = 0; k < 16; ++k) {
            float h = fmaxf(acc[k] + b3[o0 + k], 0.0f);
#pragma unroll
            for (int off = 16; off >= 1; off >>= 1)
                h = fmaxf(h, __shfl_xor(h, off, 64));
            if (n == 0)
                out[OFF_FEAT + (size_t)b * 128 * NPOINT + (size_t)(o0 + k) * NPOINT + s] = h;
        }
    }
}

extern "C" void kernel_launch(void* const* d_in, const int* in_sizes, int n_in,
                              void* d_out, int out_size, void* d_ws, size_t ws_size,
                              hipStream_t stream) {
    const float* xyz  = (const float*)d_in[0];
    const float* feat = (const float*)d_in[1];
    const float* W1   = (const float*)d_in[2];
    const float* b1   = (const float*)d_in[3];
    const float* W2   = (const float*)d_in[4];
    const float* b2   = (const float*)d_in[5];
    const float* W3   = (const float*)d_in[6];
    const float* b3   = (const float*)d_in[7];
    float* out = (float*)d_out;

    binsort_kernel<<<BATCH, 1024, 0, stream>>>(xyz, out);
    fps_kernel<<<BATCH, 1024, 0, stream>>>(xyz, out);
    ballq_kernel<<<dim3(NPOINT / 4, BATCH), 256, 0, stream>>>(xyz, out);
    mlp_kernel<<<dim3(NPOINT, BATCH), 256, 0, stream>>>(xyz, feat, W1, b1, W2, b2, W3, b3, out);
}